// Round 7
// baseline (199.643 us; speedup 1.0000x reference)
//
#include <hip/hip_runtime.h>
#include <stdint.h>

// Problem constants: t_q=64, t_k=128, b=32, n=1024
//   query (64,32,1024) f32 ; keys (128,32,1024) f32 ; Wq,Wk (1024,1024) f32
//   out0 = context (64,32,1024) f32 ; out1 = scores_softmax (64,32,128) f32

typedef __attribute__((ext_vector_type(8))) short bf16x8;
typedef __attribute__((ext_vector_type(4))) float f32x4;

#define C2_SCALE 2.8853900817779268f   // 2*log2(e)

__device__ __forceinline__ unsigned short f2bf(float x) {
    union { float f; uint32_t u; } v; v.f = x;
    uint32_t u = v.u;
    u += 0x7fffu + ((u >> 16) & 1u);   // round-to-nearest-even
    return (unsigned short)(u >> 16);
}

__device__ __forceinline__ float wave_sum(float x) {
#pragma unroll
    for (int off = 32; off; off >>= 1) x += __shfl_xor(x, off);
    return x;
}
__device__ __forceinline__ float wave_max(float x) {
#pragma unroll
    for (int off = 32; off; off >>= 1) x = fmaxf(x, __shfl_xor(x, off));
    return x;
}

// async 16B global -> LDS (wave-uniform base + lane*16 semantics)
__device__ __forceinline__ void gl2lds16(const void* g, void* l) {
    __builtin_amdgcn_global_load_lds(
        (const __attribute__((address_space(1))) void*)g,
        (__attribute__((address_space(3))) void*)l, 16, 0, 0);
}

// ---------------- f32 -> bf16 conversion of all 4 tensors -------------------
__global__ __launch_bounds__(256) void convert_kernel(
    const float* __restrict__ q, const float* __restrict__ k,
    const float* __restrict__ wq, const float* __restrict__ wk,
    unsigned short* __restrict__ qb, unsigned short* __restrict__ kb,
    unsigned short* __restrict__ wqb, unsigned short* __restrict__ wkb) {
    int idx = blockIdx.x * 256 + threadIdx.x;   // float4 index; 2097152 total
    int e = idx * 4;
    const float* src; unsigned short* dst; int off;
    if (e < 2097152)      { src = q;  dst = qb;  off = e; }
    else if (e < 6291456) { src = k;  dst = kb;  off = e - 2097152; }
    else if (e < 7340032) { src = wq; dst = wqb; off = e - 6291456; }
    else                  { src = wk; dst = wkb; off = e - 7340032; }
    float4 xv = *(const float4*)(src + off);
    ushort4 o;
    o.x = f2bf(xv.x); o.y = f2bf(xv.y); o.z = f2bf(xv.z); o.w = f2bf(xv.w);
    *(ushort4*)(dst + off) = o;
}

// ---------------- v = linear_att/||linear_att|| * ns; also sum(v) -----------
__global__ __launch_bounds__(256) void vnorm_kernel(
    const float* __restrict__ la, const float* __restrict__ ns,
    float* __restrict__ v) {
    __shared__ float red[4], red2[4];
    int tid = threadIdx.x, w = tid >> 6;
    float s = 0.f;
    for (int i = tid; i < 1024; i += 256) { float x = la[i]; s += x * x; }
    s = wave_sum(s);
    if ((tid & 63) == 0) red[w] = s;
    __syncthreads();
    float scale = rsqrtf(red[0] + red[1] + red[2] + red[3]) * ns[0];
    float vp = 0.f;
    for (int i = tid; i < 1024; i += 256) { float vv = la[i] * scale; v[i] = vv; vp += vv; }
    vp = wave_sum(vp);
    if ((tid & 63) == 0) red2[w] = vp;
    __syncthreads();
    if (tid == 0) v[1024] = red2[0] + red2[1] + red2[2] + red2[3];
}

// ---------------- combined projection GEMM: C = A * B^T (bf16 -> f32) -------
// rows 0..2047    -> pq  = qb * wqb^T                  (raw)
// rows 2048..6143 -> ek  = exp2(kb * wkb^T * C2_SCALE) (pre-exp'd for score)
// R5 single-buffered structure (R6 double-buffer regressed ~9us — reverted).
// 128x128 block tile, BK=32, 4 waves 2x2 (wave tile 64x64, acc 4x4).
__global__ __launch_bounds__(256) void proj_gemm(
    const unsigned short* __restrict__ qb, const unsigned short* __restrict__ kb,
    const unsigned short* __restrict__ wqb, const unsigned short* __restrict__ wkb,
    float* __restrict__ pq, float* __restrict__ ek) {
    __shared__ unsigned short As[128 * 32];   // 8 KB [row][k]
    __shared__ unsigned short Bs[128 * 32];   // 8 KB [col][k]
    int col0 = blockIdx.x * 128;   // 8 col tiles
    int row0 = blockIdx.y * 128;   // 48 row tiles
    const unsigned short* A; const unsigned short* Bm; float* C; int arow; bool is_k;
    if (row0 < 2048) { A = qb; Bm = wqb; C = pq; arow = row0;        is_k = false; }
    else             { A = kb; Bm = wkb; C = ek; arow = row0 - 2048; is_k = true; }
    int tid = threadIdx.x;
    int w = tid >> 6, lane = tid & 63;
    int wm = w >> 1, wn = w & 1;          // 2x2 waves
    int ml = lane & 15, quad = lane >> 4;

    // staging: flat 16B chunk c=tid -> LDS byte off c*16; row = c>>2, kchunk = c&3
    const unsigned short* ga0 = A + (arow + (tid >> 2)) * 1024 + (tid & 3) * 8;
    const unsigned short* ga1 = ga0 + 64 * 1024;
    const unsigned short* gb0 = Bm + (col0 + (tid >> 2)) * 1024 + (tid & 3) * 8;
    const unsigned short* gb1 = gb0 + 64 * 1024;
    unsigned short* la0 = &As[tid * 8];
    unsigned short* la1 = &As[(tid + 256) * 8];
    unsigned short* lb0 = &Bs[tid * 8];
    unsigned short* lb1 = &Bs[(tid + 256) * 8];

    const unsigned short* Arow = &As[(wm * 64 + ml) * 32 + quad * 8];
    const unsigned short* Brow = &Bs[(wn * 64 + ml) * 32 + quad * 8];

    f32x4 acc[4][4];
#pragma unroll
    for (int i = 0; i < 4; i++)
#pragma unroll
        for (int j = 0; j < 4; j++) acc[i][j] = (f32x4)(0.f);

    for (int k0 = 0; k0 < 1024; k0 += 32) {
        __syncthreads();                 // previous iteration's LDS reads done
        gl2lds16(ga0 + k0, la0);
        gl2lds16(ga1 + k0, la1);
        gl2lds16(gb0 + k0, lb0);
        gl2lds16(gb1 + k0, lb1);
        __syncthreads();                 // staging drained
        bf16x8 a[4], b[4];
#pragma unroll
        for (int i = 0; i < 4; i++) a[i] = *(const bf16x8*)(Arow + i * 16 * 32);
#pragma unroll
        for (int j = 0; j < 4; j++) b[j] = *(const bf16x8*)(Brow + j * 16 * 32);
#pragma unroll
        for (int i = 0; i < 4; i++)
#pragma unroll
            for (int j = 0; j < 4; j++)
                acc[i][j] = __builtin_amdgcn_mfma_f32_16x16x32_bf16(a[i], b[j], acc[i][j], 0, 0, 0);
    }

    // C/D layout: col = lane&15, row = quad*4 + reg
#pragma unroll
    for (int i = 0; i < 4; i++)
#pragma unroll
        for (int j = 0; j < 4; j++) {
            int colg = col0 + wn * 64 + j * 16 + ml;
#pragma unroll
            for (int r = 0; r < 4; r++) {
                int row = arow + wm * 64 + i * 16 + quad * 4 + r;
                float val = acc[i][j][r];
                if (is_k) val = __builtin_amdgcn_exp2f(val * C2_SCALE);
                C[row * 1024 + colg] = val;
            }
        }
}

// ---------------- fused score + softmax + context ---------------------------
// One block = one b, TQ=2 q values; 512 threads = 8 waves; grid (32 b, 32 qt)
// = 1024 blocks -> up to ~24 waves/CU (launch_bounds(512,6)).
// Pairing identity (halves rcp count):
//   v0/(1+A) + v1/(1+B) = [v0*(1+B) + v1*(1+A)] * rcp((1+A)(1+B))
// with A = ej0*ek0, B = ej1*ek1:
//   a1=fma(ej0,ek0,1); b1=fma(ej1,ek1,1); p=a1*b1; r=rcp(p);
//   num=fma(v1,a1, v0*b1); acc=fma(num,r,acc)   -> 6 VALU + 1 trans / 2 elems
// ej = exp2((pq+bias)*2log2e) in regs; ek = exp2(pk*2log2e) precomputed.
__global__ __launch_bounds__(512, 6) void score_ctx(
    const float* __restrict__ pq, const float* __restrict__ ekbuf,
    const float* __restrict__ keys, const float* __restrict__ bias,
    const float* __restrict__ v,
    float* __restrict__ out_ctx, float* __restrict__ out_sc) {
    __shared__ float sc[2][128];
    const float L2E = 1.4426950408889634f;
    int b = blockIdx.x;
    int q0 = blockIdx.y * 2;
    int tid = threadIdx.x;
    int w = tid >> 6, lane = tid & 63;   // w in 0..7

    // per-lane loop invariants: ej[j][i] for u = i*256 + lane*4 .. +3, and v
    float4 ej[2][4];
    float4 vv[4];
#pragma unroll
    for (int i = 0; i < 4; i++) {
        int u0 = i * 256 + lane * 4;
        float4 bb = *(const float4*)(bias + u0);
        vv[i] = *(const float4*)(v + u0);
#pragma unroll
        for (int j = 0; j < 2; j++) {
            float4 p = *(const float4*)(pq + ((q0 + j) * 32 + b) * 1024 + u0);
            ej[j][i].x = __builtin_amdgcn_exp2f((p.x + bb.x) * C2_SCALE);
            ej[j][i].y = __builtin_amdgcn_exp2f((p.y + bb.y) * C2_SCALE);
            ej[j][i].z = __builtin_amdgcn_exp2f((p.z + bb.z) * C2_SCALE);
            ej[j][i].w = __builtin_amdgcn_exp2f((p.w + bb.w) * C2_SCALE);
        }
    }
    float vsum = v[1024];

    // k = kk*8 + w
    const float* base = ekbuf + (w * 32 + b) * 1024 + lane * 4;
    for (int kk = 0; kk < 16; kk++) {
        int k = kk * 8 + w;
        const float* cur = base + kk * 262144;
        float a0 = 0.f, a1 = 0.f;
#pragma unroll
        for (int i = 0; i < 4; i++) {
            float4 e4 = *(const float4*)(cur + i * 256);   // ek values
            float4 v4 = vv[i];
#pragma unroll
            for (int j = 0; j < 2; j++) {
                float4 e = ej[j][i];
                float& acc = (j == 0) ? a0 : a1;
                // pair (x,y)
                float A1 = fmaf(e.x, e4.x, 1.f);
                float B1 = fmaf(e.y, e4.y, 1.f);
                float num = fmaf(v4.y, A1, v4.x * B1);
                acc = fmaf(num, __builtin_amdgcn_rcpf(A1 * B1), acc);
                // pair (z,w)
                float A2 = fmaf(e.z, e4.z, 1.f);
                float B2 = fmaf(e.w, e4.w, 1.f);
                float num2 = fmaf(v4.w, A2, v4.z * B2);
                acc = fmaf(num2, __builtin_amdgcn_rcpf(A2 * B2), acc);
            }
        }
        a0 = wave_sum(a0); a1 = wave_sum(a1);
        if (lane == 0) {
            sc[0][k] = vsum - 2.f * a0;
            sc[1][k] = vsum - 2.f * a1;
        }
    }
    __syncthreads();

    // softmax over k (128): waves 0..1 handle q-row j=w; lanes cover k, k+64
    if (w < 2) {
        int j = w;
        float s1 = sc[j][lane], s2 = sc[j][lane + 64];
        float m = wave_max(fmaxf(s1, s2));
        float e1 = __builtin_amdgcn_exp2f((s1 - m) * L2E);
        float e2 = __builtin_amdgcn_exp2f((s2 - m) * L2E);
        float ssum = wave_sum(e1 + e2);
        float inv = __builtin_amdgcn_rcpf(ssum);
        float p1 = e1 * inv, p2 = e2 * inv;
        sc[j][lane] = p1; sc[j][lane + 64] = p2;
        float* o = out_sc + ((q0 + j) * 32 + b) * 128;
        o[lane] = p1; o[lane + 64] = p2;
    }
    __syncthreads();

    // context[j][n] = sum_k p[j][k] * keys[k][b][n]; thread owns 2 n's, 2 rows
    {
        int n0 = tid * 2;
        const float* kbase = keys + b * 1024 + n0;
        float c0x = 0, c0y = 0, c1x = 0, c1y = 0;
        for (int k = 0; k < 128; k++) {
            float2 kv = *(const float2*)(kbase + k * 32768);
            float p0 = sc[0][k], p1 = sc[1][k];
            c0x = fmaf(p0, kv.x, c0x); c0y = fmaf(p0, kv.y, c0y);
            c1x = fmaf(p1, kv.x, c1x); c1y = fmaf(p1, kv.y, c1y);
        }
        float2 o;
        o.x = c0x; o.y = c0y; *(float2*)(out_ctx + ((q0 + 0) * 32 + b) * 1024 + n0) = o;
        o.x = c1x; o.y = c1y; *(float2*)(out_ctx + ((q0 + 1) * 32 + b) * 1024 + n0) = o;
    }
}

extern "C" void kernel_launch(void* const* d_in, const int* in_sizes, int n_in,
                              void* d_out, int out_size, void* d_ws, size_t ws_size,
                              hipStream_t stream) {
    const float* query = (const float*)d_in[0];
    const float* keys  = (const float*)d_in[1];
    const float* Wq    = (const float*)d_in[2];
    const float* Wk    = (const float*)d_in[3];
    const float* la    = (const float*)d_in[4];
    const float* ns    = (const float*)d_in[5];
    const float* bias  = (const float*)d_in[6];

    float* out_ctx = (float*)d_out;             // 64*32*1024
    float* out_sc  = (float*)d_out + 2097152;   // 64*32*128

    char* ws = (char*)d_ws;                     // needs ~42 MB
    float* v  = (float*)(ws);                   // 1025 floats
    float* pq = (float*)(ws + 8192);            // 8 MB
    float* ek = (float*)(ws + 8192 + 8388608);  // 16 MB
    unsigned short* qb  = (unsigned short*)(ws + 8192 + 8388608 + 16777216);
    unsigned short* kb  = qb + 2097152;
    unsigned short* wqb = kb + 4194304;
    unsigned short* wkb = wqb + 1048576;

    vnorm_kernel<<<1, 256, 0, stream>>>(la, ns, v);
    convert_kernel<<<8192, 256, 0, stream>>>(query, keys, Wq, Wk, qb, kb, wqb, wkb);
    proj_gemm<<<dim3(8, 48), 256, 0, stream>>>(qb, kb, wqb, wkb, pq, ek);
    score_ctx<<<dim3(32, 32), 512, 0, stream>>>(pq, ek, keys, bias, v, out_ctx, out_sc);
}

// Round 8
// 170.532 us; speedup vs baseline: 1.1707x; 1.1707x over previous
//
#include <hip/hip_runtime.h>
#include <stdint.h>

// Problem constants: t_q=64, t_k=128, b=32, n=1024
//   query (64,32,1024) f32 ; keys (128,32,1024) f32 ; Wq,Wk (1024,1024) f32
//   out0 = context (64,32,1024) f32 ; out1 = scores_softmax (64,32,128) f32

typedef __attribute__((ext_vector_type(8))) short bf16x8;
typedef __attribute__((ext_vector_type(4))) float f32x4;

#define C2_SCALE 2.8853900817779268f   // 2*log2(e)

__device__ __forceinline__ unsigned short f2bf(float x) {
    union { float f; uint32_t u; } v; v.f = x;
    uint32_t u = v.u;
    u += 0x7fffu + ((u >> 16) & 1u);   // round-to-nearest-even
    return (unsigned short)(u >> 16);
}

__device__ __forceinline__ float wave_sum(float x) {
#pragma unroll
    for (int off = 32; off; off >>= 1) x += __shfl_xor(x, off);
    return x;
}
__device__ __forceinline__ float wave_max(float x) {
#pragma unroll
    for (int off = 32; off; off >>= 1) x = fmaxf(x, __shfl_xor(x, off));
    return x;
}

// async 16B global -> LDS (wave-uniform base + lane*16 semantics)
__device__ __forceinline__ void gl2lds16(const void* g, void* l) {
    __builtin_amdgcn_global_load_lds(
        (const __attribute__((address_space(1))) void*)g,
        (__attribute__((address_space(3))) void*)l, 16, 0, 0);
}

// ------- f32 -> bf16 conversion of all 4 tensors + fused vnorm (blk 8192) ---
__global__ __launch_bounds__(256) void convert_kernel(
    const float* __restrict__ q, const float* __restrict__ k,
    const float* __restrict__ wq, const float* __restrict__ wk,
    unsigned short* __restrict__ qb, unsigned short* __restrict__ kb,
    unsigned short* __restrict__ wqb, unsigned short* __restrict__ wkb,
    const float* __restrict__ la, const float* __restrict__ ns,
    float* __restrict__ v) {
    __shared__ float red[4], red2[4];
    if (blockIdx.x == 8192) {
        // vnorm: v = la/||la|| * ns; v[1024] = sum(v)
        int tid = threadIdx.x, w = tid >> 6;
        float s = 0.f;
        for (int i = tid; i < 1024; i += 256) { float x = la[i]; s += x * x; }
        s = wave_sum(s);
        if ((tid & 63) == 0) red[w] = s;
        __syncthreads();
        float scale = rsqrtf(red[0] + red[1] + red[2] + red[3]) * ns[0];
        float vp = 0.f;
        for (int i = tid; i < 1024; i += 256) { float vv = la[i] * scale; v[i] = vv; vp += vv; }
        vp = wave_sum(vp);
        if ((tid & 63) == 0) red2[w] = vp;
        __syncthreads();
        if (tid == 0) v[1024] = red2[0] + red2[1] + red2[2] + red2[3];
        return;
    }
    int idx = blockIdx.x * 256 + threadIdx.x;   // float4 index; 2097152 total
    int e = idx * 4;
    const float* src; unsigned short* dst; int off;
    if (e < 2097152)      { src = q;  dst = qb;  off = e; }
    else if (e < 6291456) { src = k;  dst = kb;  off = e - 2097152; }
    else if (e < 7340032) { src = wq; dst = wqb; off = e - 6291456; }
    else                  { src = wk; dst = wkb; off = e - 7340032; }
    float4 xv = *(const float4*)(src + off);
    ushort4 o;
    o.x = f2bf(xv.x); o.y = f2bf(xv.y); o.z = f2bf(xv.z); o.w = f2bf(xv.w);
    *(ushort4*)(dst + off) = o;
}

// ---------------- combined projection GEMM: C = A * B^T (bf16 -> f32) -------
// rows 0..2047    -> pq  = qb * wqb^T                  (raw)
// rows 2048..6143 -> ek  = exp2(kb * wkb^T * C2_SCALE) (pre-exp'd for score)
// 64-row x 128-col block tile, BK=32, 4 waves 2x2 (wave tile 32x64, acc 2x4).
// Grid 8 x 96 = 768 blocks = 3 blocks/CU (R5/R7's 128x128 gave only 1.5/CU —
// occupancy theory for the barrier-bound K-loop). 12 KB LDS.
__global__ __launch_bounds__(256) void proj_gemm(
    const unsigned short* __restrict__ qb, const unsigned short* __restrict__ kb,
    const unsigned short* __restrict__ wqb, const unsigned short* __restrict__ wkb,
    float* __restrict__ pq, float* __restrict__ ek) {
    __shared__ unsigned short As[64 * 32];    // 4 KB [row][k]
    __shared__ unsigned short Bs[128 * 32];   // 8 KB [col][k]
    int col0 = blockIdx.x * 128;   // 8 col tiles
    int row0 = blockIdx.y * 64;    // 96 row tiles
    const unsigned short* A; const unsigned short* Bm; float* C; int arow; bool is_k;
    if (row0 < 2048) { A = qb; Bm = wqb; C = pq; arow = row0;        is_k = false; }
    else             { A = kb; Bm = wkb; C = ek; arow = row0 - 2048; is_k = true; }
    int tid = threadIdx.x;
    int w = tid >> 6, lane = tid & 63;
    int wm = w >> 1, wn = w & 1;          // 2x2 waves
    int ml = lane & 15, quad = lane >> 4;

    // staging: flat 16B chunk c=tid -> LDS byte off c*16; row = c>>2, kchunk = c&3
    const unsigned short* ga0 = A + (arow + (tid >> 2)) * 1024 + (tid & 3) * 8;
    const unsigned short* gb0 = Bm + (col0 + (tid >> 2)) * 1024 + (tid & 3) * 8;
    const unsigned short* gb1 = gb0 + 64 * 1024;
    unsigned short* la0 = &As[tid * 8];
    unsigned short* lb0 = &Bs[tid * 8];
    unsigned short* lb1 = &Bs[(tid + 256) * 8];

    const unsigned short* Arow = &As[(wm * 32 + ml) * 32 + quad * 8];
    const unsigned short* Brow = &Bs[(wn * 64 + ml) * 32 + quad * 8];

    f32x4 acc[2][4];
#pragma unroll
    for (int i = 0; i < 2; i++)
#pragma unroll
        for (int j = 0; j < 4; j++) acc[i][j] = (f32x4)(0.f);

    for (int k0 = 0; k0 < 1024; k0 += 32) {
        __syncthreads();                 // previous iteration's LDS reads done
        gl2lds16(ga0 + k0, la0);
        gl2lds16(gb0 + k0, lb0);
        gl2lds16(gb1 + k0, lb1);
        __syncthreads();                 // staging drained
        bf16x8 a[2], b[4];
#pragma unroll
        for (int i = 0; i < 2; i++) a[i] = *(const bf16x8*)(Arow + i * 16 * 32);
#pragma unroll
        for (int j = 0; j < 4; j++) b[j] = *(const bf16x8*)(Brow + j * 16 * 32);
#pragma unroll
        for (int i = 0; i < 2; i++)
#pragma unroll
            for (int j = 0; j < 4; j++)
                acc[i][j] = __builtin_amdgcn_mfma_f32_16x16x32_bf16(a[i], b[j], acc[i][j], 0, 0, 0);
    }

    // C/D layout: col = lane&15, row = quad*4 + reg
#pragma unroll
    for (int i = 0; i < 2; i++)
#pragma unroll
        for (int j = 0; j < 4; j++) {
            int colg = col0 + wn * 64 + j * 16 + ml;
#pragma unroll
            for (int r = 0; r < 4; r++) {
                int row = arow + wm * 32 + i * 16 + quad * 4 + r;
                float val = acc[i][j][r];
                if (is_k) val = __builtin_amdgcn_exp2f(val * C2_SCALE);
                C[row * 1024 + colg] = val;
            }
        }
}

// ---------------- fused score + softmax + context ---------------------------
// R6 structure (TQ=4, 512 threads, grid (32,16)=512 blocks — the proven
// L2-friendly shape; R7's TQ=2 doubled ek streaming and regressed) plus the
// u-pairing identity:
//   v0/(1+A) + v1/(1+B) = [v0*B1 + v1*A1] * rcp(A1*B1),  A1=1+A, B1=1+B
// -> 7 insts / 1 rcp per 2 elements (R6: 6 insts / 2 rcp). Denominator
// bounded by ~e^70 < fp32 max — no overflow.
// ej = exp2((pq+bias)*2log2e) in regs; ek = exp2(pk*2log2e) precomputed.
__global__ __launch_bounds__(512, 4) void score_ctx(
    const float* __restrict__ pq, const float* __restrict__ ekbuf,
    const float* __restrict__ keys, const float* __restrict__ bias,
    const float* __restrict__ v,
    float* __restrict__ out_ctx, float* __restrict__ out_sc) {
    __shared__ float sc[4][128];
    const float L2E = 1.4426950408889634f;
    int b = blockIdx.x;
    int q0 = blockIdx.y * 4;
    int tid = threadIdx.x;
    int w = tid >> 6, lane = tid & 63;   // w in 0..7

    // per-lane loop invariants: ej[j][i] for u = i*256 + lane*4 .. +3, and v
    float4 ej[4][4];
    float4 vv[4];
#pragma unroll
    for (int i = 0; i < 4; i++) {
        int u0 = i * 256 + lane * 4;
        float4 bb = *(const float4*)(bias + u0);
        vv[i] = *(const float4*)(v + u0);
#pragma unroll
        for (int j = 0; j < 4; j++) {
            float4 p = *(const float4*)(pq + ((q0 + j) * 32 + b) * 1024 + u0);
            ej[j][i].x = __builtin_amdgcn_exp2f((p.x + bb.x) * C2_SCALE);
            ej[j][i].y = __builtin_amdgcn_exp2f((p.y + bb.y) * C2_SCALE);
            ej[j][i].z = __builtin_amdgcn_exp2f((p.z + bb.z) * C2_SCALE);
            ej[j][i].w = __builtin_amdgcn_exp2f((p.w + bb.w) * C2_SCALE);
        }
    }
    float vsum = v[1024];

    // k = kk*8 + w
    const float* base = ekbuf + (w * 32 + b) * 1024 + lane * 4;
    for (int kk = 0; kk < 16; kk++) {
        int k = kk * 8 + w;
        const float* cur = base + kk * 262144;
        float a0 = 0.f, a1 = 0.f, a2 = 0.f, a3 = 0.f;
#pragma unroll
        for (int i = 0; i < 4; i++) {
            float4 e4 = *(const float4*)(cur + i * 256);   // ek values
            float4 v4 = vv[i];
#pragma unroll
            for (int j = 0; j < 4; j++) {
                float4 e = ej[j][i];
                float acc = (j == 0) ? a0 : (j == 1) ? a1 : (j == 2) ? a2 : a3;
                // pair (x,y)
                float A1 = fmaf(e.x, e4.x, 1.f);
                float B1 = fmaf(e.y, e4.y, 1.f);
                float num = fmaf(v4.x, B1, v4.y * A1);
                acc = fmaf(num, __builtin_amdgcn_rcpf(A1 * B1), acc);
                // pair (z,w)
                float A2 = fmaf(e.z, e4.z, 1.f);
                float B2 = fmaf(e.w, e4.w, 1.f);
                float num2 = fmaf(v4.z, B2, v4.w * A2);
                acc = fmaf(num2, __builtin_amdgcn_rcpf(A2 * B2), acc);
                if (j == 0) a0 = acc; else if (j == 1) a1 = acc;
                else if (j == 2) a2 = acc; else a3 = acc;
            }
        }
        a0 = wave_sum(a0); a1 = wave_sum(a1); a2 = wave_sum(a2); a3 = wave_sum(a3);
        if (lane == 0) {
            sc[0][k] = vsum - 2.f * a0;
            sc[1][k] = vsum - 2.f * a1;
            sc[2][k] = vsum - 2.f * a2;
            sc[3][k] = vsum - 2.f * a3;
        }
    }
    __syncthreads();

    // softmax over k (128): waves 0..3 handle q-row j=w; lanes cover k, k+64
    if (w < 4) {
        int j = w;
        float s1 = sc[j][lane], s2 = sc[j][lane + 64];
        float m = wave_max(fmaxf(s1, s2));
        float e1 = __builtin_amdgcn_exp2f((s1 - m) * L2E);
        float e2 = __builtin_amdgcn_exp2f((s2 - m) * L2E);
        float ssum = wave_sum(e1 + e2);
        float inv = __builtin_amdgcn_rcpf(ssum);
        float p1 = e1 * inv, p2 = e2 * inv;
        sc[j][lane] = p1; sc[j][lane + 64] = p2;
        float* o = out_sc + ((q0 + j) * 32 + b) * 128;
        o[lane] = p1; o[lane + 64] = p2;
    }
    __syncthreads();

    // context[j][n] = sum_k p[j][k] * keys[k][b][n]; thread owns 2 n's, 4 rows
    {
        int n0 = tid * 2;
        const float* kbase = keys + b * 1024 + n0;
        float c0x = 0, c0y = 0, c1x = 0, c1y = 0;
        float c2x = 0, c2y = 0, c3x = 0, c3y = 0;
        for (int k = 0; k < 128; k++) {
            float2 kv = *(const float2*)(kbase + k * 32768);
            float p0 = sc[0][k], p1 = sc[1][k], p2 = sc[2][k], p3 = sc[3][k];
            c0x = fmaf(p0, kv.x, c0x); c0y = fmaf(p0, kv.y, c0y);
            c1x = fmaf(p1, kv.x, c1x); c1y = fmaf(p1, kv.y, c1y);
            c2x = fmaf(p2, kv.x, c2x); c2y = fmaf(p2, kv.y, c2y);
            c3x = fmaf(p3, kv.x, c3x); c3y = fmaf(p3, kv.y, c3y);
        }
        float2 o;
        o.x = c0x; o.y = c0y; *(float2*)(out_ctx + ((q0 + 0) * 32 + b) * 1024 + n0) = o;
        o.x = c1x; o.y = c1y; *(float2*)(out_ctx + ((q0 + 1) * 32 + b) * 1024 + n0) = o;
        o.x = c2x; o.y = c2y; *(float2*)(out_ctx + ((q0 + 2) * 32 + b) * 1024 + n0) = o;
        o.x = c3x; o.y = c3y; *(float2*)(out_ctx + ((q0 + 3) * 32 + b) * 1024 + n0) = o;
    }
}

extern "C" void kernel_launch(void* const* d_in, const int* in_sizes, int n_in,
                              void* d_out, int out_size, void* d_ws, size_t ws_size,
                              hipStream_t stream) {
    const float* query = (const float*)d_in[0];
    const float* keys  = (const float*)d_in[1];
    const float* Wq    = (const float*)d_in[2];
    const float* Wk    = (const float*)d_in[3];
    const float* la    = (const float*)d_in[4];
    const float* ns    = (const float*)d_in[5];
    const float* bias  = (const float*)d_in[6];

    float* out_ctx = (float*)d_out;             // 64*32*1024
    float* out_sc  = (float*)d_out + 2097152;   // 64*32*128

    char* ws = (char*)d_ws;                     // needs ~42 MB
    float* v  = (float*)(ws);                   // 1025 floats
    float* pq = (float*)(ws + 8192);            // 8 MB
    float* ek = (float*)(ws + 8192 + 8388608);  // 16 MB
    unsigned short* qb  = (unsigned short*)(ws + 8192 + 8388608 + 16777216);
    unsigned short* kb  = qb + 2097152;
    unsigned short* wqb = kb + 4194304;
    unsigned short* wkb = wqb + 1048576;

    convert_kernel<<<8193, 256, 0, stream>>>(query, keys, Wq, Wk, qb, kb, wqb, wkb,
                                             la, ns, v);
    proj_gemm<<<dim3(8, 96), 256, 0, stream>>>(qb, kb, wqb, wkb, pq, ek);
    score_ctx<<<dim3(32, 16), 512, 0, stream>>>(pq, ek, keys, bias, v, out_ctx, out_sc);
}